// Round 3
// baseline (115.084 us; speedup 1.0000x reference)
//
#include <hip/hip_runtime.h>

#define BATCH 2
#define H 512
#define W 512
#define CS 21
#define CI 3
#define P 32                    // pixels per block (x)
#define R 8                     // output rows per block (vertical run)
#define TPB 192                 // 6 threads/pixel, 3 waves
#define GROWS (R + 2)           // 10 tap rows

typedef float f32x4 __attribute__((ext_vector_type(4)));

__device__ __forceinline__ void fma4(float4& a, const float4 v, const float w) {
    a.x = fmaf(v.x, w, a.x);
    a.y = fmaf(v.y, w, a.y);
    a.z = fmaf(v.z, w, a.z);
    a.w = fmaf(v.w, w, a.w);
}

// out is never re-read: nt store avoids L2 write-allocate evicting src/guide.
__device__ __forceinline__ void nt_store4(float* p, const float4 v) {
    __builtin_nontemporal_store(*(const f32x4*)&v, (f32x4*)p);
}

__device__ __forceinline__ int refl(int v) {
    return (v < 0) ? 1 : ((v >= H) ? 2 * H - 2 - v : v);
}

// Barrier-free rolling kernel. No LDS, no __syncthreads. Each thread owns one
// (pixel, channel-chunk) and walks 8 output rows with a 4-slot register
// window (3 src float4 + 3x3 guide floats per row), software-pipelined one
// row ahead. Weights recomputed per-thread (x6 exp dup) -- VALU was 12% busy,
// trading idle VALU for the removal of both barriers + the 49KB weight LDS.
// Stores begin after ~1 row of loads, so the compulsory 44MB HBM write stream
// (the roofline floor) starts immediately instead of after the staged head.
__global__ __launch_bounds__(TPB, 6) void jbu_kernel(
    const float* __restrict__ src, const float* __restrict__ im,
    float* __restrict__ out)
{
    const int t = threadIdx.x;

    // XCD swizzle: XCD (f&7) owns a contiguous 64-output-row band so
    // vertically adjacent blocks share halo rows in the same L2.
    const int f      = blockIdx.x;        // 0..2047
    const int xcd    = f & 7;
    const int g      = f >> 3;            // 0..255
    const int rowgrp = (xcd << 3) | (g & 7);   // 0..63
    const int rem    = g >> 3;            // 0..31
    const int x0     = (rem & 15) << 5;   // 16 x-segments * 32 px
    const int b      = rem >> 4;          // batch
    const int y0     = rowgrp << 3;       // output rows y0..y0+7

    const int px   = t / 6;               // 0..31
    const int q    = t - px * 6;
    const int coff = (q == 5) ? 17 : (q << 2);
    const int x    = x0 + px;
    const int xm   = (x == 0)     ? 1     : x - 1;
    const int xp   = (x == W - 1) ? W - 2 : x + 1;

    const size_t rs  = (size_t)W * CS;
    const float* sb  = src + (size_t)b * H * rs;
    const float* imb = im  + (size_t)b * (size_t)(H * W * CI);
    const int om = xm * CS + coff;        // absolute float offsets within a row
    const int oc = x  * CS + coff;
    const int op = xp * CS + coff;
    const int gm = xm * CI;
    const int gc = x  * CI;
    const int gp = xp * CI;

    float* ob = out + ((size_t)(b * H + y0)) * rs;

    float4 s[4][3];        // [slot][xtap] src window
    float  gg[4][3][3];    // [slot][xtap][ch] guide window

    const float w1k[9] = {0.36787944f, 0.60653066f, 0.36787944f,
                          0.60653066f, 1.0f,        0.60653066f,
                          0.36787944f, 0.60653066f, 0.36787944f};

    // Load tap row rr into window slot sl (3 f4 + 9 contiguous-mergeable floats).
#define LOADROW(rr, sl)                                                       \
    {                                                                         \
        const int    ry = refl(y0 - 1 + (rr));                                \
        const float* sr = sb  + (size_t)ry * rs;                              \
        const float* gr = imb + (size_t)ry * (W * CI);                        \
        s[sl][0] = *(const float4*)(sr + om);                                 \
        s[sl][1] = *(const float4*)(sr + oc);                                 \
        s[sl][2] = *(const float4*)(sr + op);                                 \
        gg[sl][0][0] = gr[gm]; gg[sl][0][1] = gr[gm + 1]; gg[sl][0][2] = gr[gm + 2]; \
        gg[sl][1][0] = gr[gc]; gg[sl][1][1] = gr[gc + 1]; gg[sl][1][2] = gr[gc + 2]; \
        gg[sl][2][0] = gr[gp]; gg[sl][2][1] = gr[gp + 1]; gg[sl][2][2] = gr[gp + 2]; \
    }

    // Prime rows 0..2 (slots 0..2).
    LOADROW(0, 0)
    LOADROW(1, 1)
    LOADROW(2, 2)

    #pragma unroll
    for (int j = 0; j < R; ++j) {
        // Software pipeline: issue next tap row's loads before this row's math.
        if (j < R - 1) {
            const int sl = (j + 3) & 3;       // compile-time after unroll
            LOADROW(j + 3, sl)
        }

        const int s0 = (j + 0) & 3;
        const int s1 = (j + 1) & 3;
        const int s2 = (j + 2) & 3;

        const float c0 = gg[s1][1][0];
        const float c1 = gg[s1][1][1];
        const float c2 = gg[s1][1][2];

        float wv[9];
        float den = 0.f;
        #pragma unroll
        for (int k = 0; k < 9; ++k) {
            const int dy = k / 3, dx = k % 3;
            const int sl = (dy == 0) ? s0 : ((dy == 1) ? s1 : s2);
            const float d0 = gg[sl][dx][0] - c0;
            const float d1 = gg[sl][dx][1] - c1;
            const float d2 = gg[sl][dx][2] - c2;
            const float w = __expf(-8.0f * (d0 * d0 + d1 * d1 + d2 * d2)) * w1k[k];
            wv[k] = w;
            den += w;
        }
        const float inv = 1.0f / den;

        float4 acc = {0.f, 0.f, 0.f, 0.f};
        #pragma unroll
        for (int k = 0; k < 9; ++k) {
            const int dy = k / 3, dx = k % 3;
            const int sl = (dy == 0) ? s0 : ((dy == 1) ? s1 : s2);
            fma4(acc, s[sl][dx], wv[k] * inv);
        }
        nt_store4(ob + (size_t)j * rs + oc, acc);
    }
#undef LOADROW
}

extern "C" void kernel_launch(void* const* d_in, const int* in_sizes, int n_in,
                              void* d_out, int out_size, void* d_ws, size_t ws_size,
                              hipStream_t stream) {
    const float* src = (const float*)d_in[0];
    const float* im  = (const float*)d_in[1];
    float* out = (float*)d_out;
    dim3 grid((W / P) * (H / R) * BATCH, 1, 1);   // 2048 blocks = 8/CU, 24 waves/CU
    jbu_kernel<<<grid, TPB, 0, stream>>>(src, im, out);
}

// Round 4
// 106.309 us; speedup vs baseline: 1.0825x; 1.0825x over previous
//
#include <hip/hip_runtime.h>

#define BATCH 2
#define H 512
#define W 512
#define CS 21
#define CI 3
#define P 128                   // pixels per block (x)
#define R 8                     // output rows per block (vertical run)
#define TPB 384                 // 6 waves/block; 2 blocks/CU -> 12 waves/CU
#define GROWS (R + 2)           // 10 tap rows
#define GSL (P + 2)             // 130 guide slots incl. halo
#define GSZ (GROWS * GSL * CI)  // 3900 guide floats

typedef float f32x4 __attribute__((ext_vector_type(4)));

__device__ __forceinline__ void fma4(float4& a, const float4 v, const float w) {
    a.x = fmaf(v.x, w, a.x);
    a.y = fmaf(v.y, w, a.y);
    a.z = fmaf(v.z, w, a.z);
    a.w = fmaf(v.w, w, a.w);
}

// out is never re-read: nt store avoids L2 write-allocate evicting src halo.
__device__ __forceinline__ void nt_store4(float* p, const float4 v) {
    __builtin_nontemporal_store(*(const f32x4*)&v, (f32x4*)p);
}

// Load the 3 x-taps of one src row into a float4[3].
#define LOAD3(dst, rr, om, oc, op)                              \
    (dst)[0] = *(const float4*)(srow[rr] + (om));               \
    (dst)[1] = *(const float4*)(srow[rr] + (oc));               \
    (dst)[2] = *(const float4*)(srow[rr] + (op));

// Row selector: rows 0..5 live in va[6][3], rows 6..9 in vb[4][3].
#define VA_I(r) ((r) < 6 ? (r) : 5)
#define VB_I(r) ((r) < 6 ? 0 : (r) - 6)
#define VR(va, vb, r, k) ((r) < 6 ? (va)[VA_I(r)][(k)] : (vb)[VB_I(r)][(k)])

// 8-row vertical run: same fma ordering as R2 (bit-identical output).
#define COMPUTE8(va, vb, px, oc)                                             \
    {                                                                        \
        _Pragma("unroll")                                                    \
        for (int j = 0; j < R; ++j) {                                        \
            const float* wd = &s_w[((j << 7) + (px)) * 12];                  \
            float4 wA = *(const float4*)(wd + 0);                            \
            float4 wB = *(const float4*)(wd + 4);                            \
            float  w8 = wd[8];                                               \
            float4 acc = {0.f, 0.f, 0.f, 0.f};                               \
            fma4(acc, VR(va, vb, j + 0, 0), wA.x);                           \
            fma4(acc, VR(va, vb, j + 0, 1), wA.y);                           \
            fma4(acc, VR(va, vb, j + 0, 2), wA.z);                           \
            fma4(acc, VR(va, vb, j + 1, 0), wA.w);                           \
            fma4(acc, VR(va, vb, j + 1, 1), wB.x);                           \
            fma4(acc, VR(va, vb, j + 1, 2), wB.y);                           \
            fma4(acc, VR(va, vb, j + 2, 0), wB.z);                           \
            fma4(acc, VR(va, vb, j + 2, 1), wB.w);                           \
            fma4(acc, VR(va, vb, j + 2, 2), w8);                             \
            nt_store4(ob + (size_t)j * rs + (oc), acc);                      \
        }                                                                    \
    }

// R2 structure (LDS-shared weights, async guide stage, prefetch overlap),
// TPB 256->384: same 64.75KB LDS so still 2 blocks/CU and all 512 blocks
// co-resident, but 12 waves/CU (3/SIMD) instead of 8 for latency hiding.
__global__ __launch_bounds__(TPB, 3) void jbu_kernel(
    const float* __restrict__ src, const float* __restrict__ im,
    float* __restrict__ out)
{
    __shared__ float s_g[GSZ];                       // 15,600 B guide tile
    __shared__ __align__(16) float s_w[R * P * 12];  // 49,152 B weights

    const int t = threadIdx.x;

    // XCD swizzle: XCD (f&7) owns a contiguous 64-output-row band.
    const int f      = blockIdx.x;        // 0..511
    const int xcd    = f & 7;
    const int g      = f >> 3;            // 0..63
    const int rowgrp = (xcd << 3) | (g & 7);    // 0..63
    const int rem    = g >> 3;            // 0..7
    const int x0     = (rem & 3) << 7;    // segment * 128
    const int b      = rem >> 2;
    const int y0     = rowgrp << 3;       // output rows y0..y0+7

    const size_t rs = (size_t)W * CS;
    const float* sb = src + (size_t)b * H * rs;
    const float* srow[GROWS];
    #pragma unroll
    for (int rr = 0; rr < GROWS; ++rr) {
        int v = y0 - 1 + rr;
        int tyr = (v < 0) ? 1 : ((v >= H) ? 2 * H - 2 - v : v);
        srow[rr] = sb + (size_t)tyr * rs + (size_t)x0 * CS;
    }

    // ---- it=0 addressing + full 6-row prefetch (rows 0..5) ----
    const int px0   = t / 6;              // 0..63
    const int q0    = t - px0 * 6;
    const int coff0 = (q0 == 5) ? 17 : (q0 << 2);
    const int x_    = x0 + px0;
    const int xm_   = (x_ == 0)     ? 1     : x_ - 1;
    const int xp_   = (x_ == W - 1) ? W - 2 : x_ + 1;
    const int om0   = (xm_ - x0) * CS + coff0;   // may be negative: valid in-row
    const int oc0   = px0 * CS + coff0;
    const int op0   = (xp_ - x0) * CS + coff0;

    float4 va0[6][3];
    #pragma unroll
    for (int rr = 0; rr < 6; ++rr) { LOAD3(va0[rr], rr, om0, oc0, op0) }

    // ---- stage guide tile: async global->LDS (linear dest = base + lane*4) ----
    const float* imb = im + (size_t)b * (H * W * CI);
    for (int i = t; i < GSZ; i += TPB) {
        int rr   = i / (GSL * CI);
        int remi = i - rr * (GSL * CI);
        int slot = remi / CI;
        int ch   = remi - slot * CI;
        int gx   = x0 + slot - 1;
        gx = (gx < 0) ? 1 : ((gx >= W) ? W - 2 : gx);
        int vv = y0 - 1 + rr;
        int tyr = (vv < 0) ? 1 : ((vv >= H) ? 2 * H - 2 - vv : vv);
        const float* gsrc = imb + ((size_t)tyr * W + gx) * CI + ch;
        __builtin_amdgcn_global_load_lds(
            (const __attribute__((address_space(1))) void*)gsrc,
            (__attribute__((address_space(3))) void*)(s_g + i), 4, 0, 0);
    }
    __syncthreads();

    // ---- it=1 addressing + rows 0..3 prefetch: streams during weight phase ----
    const int item1 = TPB + t;            // 384..767
    const int px1   = item1 / 6;          // 64..127
    const int q1    = item1 - px1 * 6;
    const int coff1 = (q1 == 5) ? 17 : (q1 << 2);
    const int x1    = x0 + px1;
    const int xm1   = (x1 == 0)     ? 1     : x1 - 1;
    const int xp1   = (x1 == W - 1) ? W - 2 : x1 + 1;
    const int om1   = (xm1 - x0) * CS + coff1;
    const int oc1   = px1 * CS + coff1;
    const int op1   = (xp1 - x0) * CS + coff1;

    float4 va1[6][3];
    #pragma unroll
    for (int rr = 0; rr < 4; ++rr) { LOAD3(va1[rr], rr, om1, oc1, op1) }

    // ---- weights: R*P = 1024 sets, ceil(1024/384)=3 iters, normalized ----
    {
        const float w1k[9] = {0.36787944f, 0.60653066f, 0.36787944f,
                              0.60653066f, 1.0f,        0.60653066f,
                              0.36787944f, 0.60653066f, 0.36787944f};
        #pragma unroll
        for (int ii = 0; ii < 3; ++ii) {
            int idx = ii * TPB + t;       // 0..1151
            if (idx < R * P) {
                int r   = idx >> 7;       // 0..7   (idx / P)
                int px  = idx & (P - 1);
                int cb  = ((r + 1) * GSL + px + 1) * CI;
                float c0 = s_g[cb + 0], c1 = s_g[cb + 1], c2 = s_g[cb + 2];
                float wv[9];
                float den = 0.f;
                #pragma unroll
                for (int k = 0; k < 9; ++k) {
                    int dy = k / 3, dx = k % 3;
                    int ib = ((r + dy) * GSL + px + dx) * CI;
                    float d0 = s_g[ib + 0] - c0;
                    float d1 = s_g[ib + 1] - c1;
                    float d2 = s_g[ib + 2] - c2;
                    float w = __expf(-8.0f * (d0 * d0 + d1 * d1 + d2 * d2)) * w1k[k];
                    wv[k] = w;
                    den += w;
                }
                float inv = 1.0f / den;
                float* wd = &s_w[idx * 12];
                *(float4*)(wd + 0) = make_float4(wv[0] * inv, wv[1] * inv, wv[2] * inv, wv[3] * inv);
                *(float4*)(wd + 4) = make_float4(wv[4] * inv, wv[5] * inv, wv[6] * inv, wv[7] * inv);
                wd[8] = wv[8] * inv;
            }
        }
    }
    __syncthreads();

    // ---- phase 2: 8-row vertical runs, taps from global, weights from LDS ----
    float* ob = out + ((size_t)(b * H + y0)) * rs + (size_t)x0 * CS;

    // it = 0: va0 ready; fetch rows 6..9 (hidden under early-j fmas)
    {
        float4 vb0[4][3];
        #pragma unroll
        for (int rr = 0; rr < 4; ++rr) { LOAD3(vb0[rr], rr + 6, om0, oc0, op0) }
        COMPUTE8(va0, vb0, px0, oc0)
    }

    // it = 1: rows 0..3 prefetched; fetch rows 4..9
    {
        LOAD3(va1[4], 4, om1, oc1, op1)
        LOAD3(va1[5], 5, om1, oc1, op1)
        float4 vb1[4][3];
        #pragma unroll
        for (int rr = 0; rr < 4; ++rr) { LOAD3(vb1[rr], rr + 6, om1, oc1, op1) }
        COMPUTE8(va1, vb1, px1, oc1)
    }
}

extern "C" void kernel_launch(void* const* d_in, const int* in_sizes, int n_in,
                              void* d_out, int out_size, void* d_ws, size_t ws_size,
                              hipStream_t stream) {
    const float* src = (const float*)d_in[0];
    const float* im  = (const float*)d_in[1];
    float* out = (float*)d_out;
    dim3 grid((W / P) * (H / R) * BATCH, 1, 1);   // 512 blocks = 2/CU
    jbu_kernel<<<grid, TPB, 0, stream>>>(src, im, out);
}

// Round 5
// 102.824 us; speedup vs baseline: 1.1192x; 1.0339x over previous
//
#include <hip/hip_runtime.h>

#define BATCH 2
#define H 512
#define W 512
#define CS 21
#define CI 3
#define P 32                    // pixels per block (x)
#define R 8                     // output rows per block (vertical run)
#define TPB 192                 // 3 waves/block; phase2 = 1 item/thread
#define GROWS (R + 2)           // 10 tap rows
#define GSL (P + 2)             // 34 guide slots incl. halo
#define GSZ (GROWS * GSL * CI)  // 1020 guide floats
#define NSETS (R * P)           // 256 weight sets
#define SWF (NSETS * 12)        // 3072 floats = 12,288 B union LDS

typedef float f32x4 __attribute__((ext_vector_type(4)));

__device__ __forceinline__ void fma4(float4& a, const float4 v, const float w) {
    a.x = fmaf(v.x, w, a.x);
    a.y = fmaf(v.y, w, a.y);
    a.z = fmaf(v.z, w, a.z);
    a.w = fmaf(v.w, w, a.w);
}

// out is never re-read: nt store avoids L2 write-allocate evicting src halo.
__device__ __forceinline__ void nt_store4(float* p, const float4 v) {
    __builtin_nontemporal_store(*(const f32x4*)&v, (f32x4*)p);
}

// Load the 3 x-taps of one src row into a float4[3].
#define LOAD3(dst, rr, om, oc, op)                              \
    (dst)[0] = *(const float4*)(srow[rr] + (om));               \
    (dst)[1] = *(const float4*)(srow[rr] + (oc));               \
    (dst)[2] = *(const float4*)(srow[rr] + (op));

// Row selector: rows 0..5 live in va[6][3], rows 6..9 in vb[4][3].
#define VA_I(r) ((r) < 6 ? (r) : 5)
#define VB_I(r) ((r) < 6 ? 0 : (r) - 6)
#define VR(va, vb, r, k) ((r) < 6 ? (va)[VA_I(r)][(k)] : (vb)[VB_I(r)][(k)])

// 8-row vertical run: same fma ordering as R2 (bit-identical output).
#define COMPUTE8(va, vb, px, oc)                                             \
    {                                                                        \
        _Pragma("unroll")                                                    \
        for (int j = 0; j < R; ++j) {                                        \
            const float* wd = &s_u[((j * P) + (px)) * 12];                   \
            float4 wA = *(const float4*)(wd + 0);                            \
            float4 wB = *(const float4*)(wd + 4);                            \
            float  w8 = wd[8];                                               \
            float4 acc = {0.f, 0.f, 0.f, 0.f};                               \
            fma4(acc, VR(va, vb, j + 0, 0), wA.x);                           \
            fma4(acc, VR(va, vb, j + 0, 1), wA.y);                           \
            fma4(acc, VR(va, vb, j + 0, 2), wA.z);                           \
            fma4(acc, VR(va, vb, j + 1, 0), wA.w);                           \
            fma4(acc, VR(va, vb, j + 1, 1), wB.x);                           \
            fma4(acc, VR(va, vb, j + 1, 2), wB.y);                           \
            fma4(acc, VR(va, vb, j + 2, 0), wB.z);                           \
            fma4(acc, VR(va, vb, j + 2, 1), wB.w);                           \
            fma4(acc, VR(va, vb, j + 2, 2), w8);                             \
            nt_store4(ob + (size_t)j * rs + (oc), acc);                      \
        }                                                                    \
    }

// R2 structure with LDS-union occupancy fix: guide tile and weight table
// share one 12.3KB LDS region (guide is dead once weights are computed in
// registers; a barrier separates last guide read from first weight write).
// P=32 tiles -> 2048 blocks, 4+ blocks/CU resident, 12+ waves/CU (vs R2's 8)
// with launch_bounds(192,3) keeping VGPRs at <=168 (R4 spill lesson: don't
// exceed the cap with prefetch state; live peak here ~150).
__global__ __launch_bounds__(TPB, 3) void jbu_kernel(
    const float* __restrict__ src, const float* __restrict__ im,
    float* __restrict__ out)
{
    __shared__ __align__(16) float s_u[SWF];   // union: guide tile, then weights

    const int t = threadIdx.x;

    // XCD swizzle: XCD (f&7) owns a contiguous 64-output-row band.
    const int f      = blockIdx.x;        // 0..2047
    const int xcd    = f & 7;
    const int g      = f >> 3;            // 0..255
    const int rowgrp = (xcd << 3) | (g & 7);   // 0..63
    const int rem    = g >> 3;            // 0..31
    const int x0     = (rem & 15) << 5;   // 16 x-segments * 32 px
    const int b      = rem >> 4;          // batch
    const int y0     = rowgrp << 3;       // output rows y0..y0+7

    const size_t rs = (size_t)W * CS;
    const float* sb = src + (size_t)b * H * rs;
    const float* srow[GROWS];             // wave-uniform -> SGPRs
    #pragma unroll
    for (int rr = 0; rr < GROWS; ++rr) {
        int v = y0 - 1 + rr;
        int tyr = (v < 0) ? 1 : ((v >= H) ? 2 * H - 2 - v : v);
        srow[rr] = sb + (size_t)tyr * rs + (size_t)x0 * CS;
    }

    // ---- phase-2 addressing (1 item/thread) + rows 0..3 prefetch ----
    const int px0   = t / 6;              // 0..31
    const int q0    = t - px0 * 6;
    const int coff0 = (q0 == 5) ? 17 : (q0 << 2);
    const int x_    = x0 + px0;
    const int xm_   = (x_ == 0)     ? 1     : x_ - 1;
    const int xp_   = (x_ == W - 1) ? W - 2 : x_ + 1;
    const int om0   = (xm_ - x0) * CS + coff0;   // may be negative: valid in-row
    const int oc0   = px0 * CS + coff0;
    const int op0   = (xp_ - x0) * CS + coff0;

    float4 va0[6][3];
    #pragma unroll
    for (int rr = 0; rr < 4; ++rr) { LOAD3(va0[rr], rr, om0, oc0, op0) }

    // ---- stage guide tile into s_u[0..GSZ): async global->LDS ----
    const float* imb = im + (size_t)b * (H * W * CI);
    #pragma unroll
    for (int ii = 0; ii < (GSZ + TPB - 1) / TPB; ++ii) {
        int i = ii * TPB + t;
        if (i < GSZ) {
            int rr   = i / (GSL * CI);
            int remi = i - rr * (GSL * CI);
            int slot = remi / CI;
            int ch   = remi - slot * CI;
            int gx   = x0 + slot - 1;
            gx = (gx < 0) ? 1 : ((gx >= W) ? W - 2 : gx);
            int vv = y0 - 1 + rr;
            int tyr = (vv < 0) ? 1 : ((vv >= H) ? 2 * H - 2 - vv : vv);
            const float* gsrc = imb + ((size_t)tyr * W + gx) * CI + ch;
            __builtin_amdgcn_global_load_lds(
                (const __attribute__((address_space(1))) void*)gsrc,
                (__attribute__((address_space(3))) void*)(s_u + i), 4, 0, 0);
        }
    }
    __syncthreads();

    // ---- weights into REGISTERS (guide still live in s_u) ----
    // NSETS=256 sets, 2 iters (iter1: t<64). Same math/order as R2.
    float wreg[2][9];
    {
        const float w1k[9] = {0.36787944f, 0.60653066f, 0.36787944f,
                              0.60653066f, 1.0f,        0.60653066f,
                              0.36787944f, 0.60653066f, 0.36787944f};
        #pragma unroll
        for (int ii = 0; ii < 2; ++ii) {
            int idx = ii * TPB + t;       // 0..383
            if (idx < NSETS) {
                int r   = idx >> 5;       // 0..7   (idx / P)
                int px  = idx & (P - 1);
                int cb  = ((r + 1) * GSL + px + 1) * CI;
                float c0 = s_u[cb + 0], c1 = s_u[cb + 1], c2 = s_u[cb + 2];
                float wv[9];
                float den = 0.f;
                #pragma unroll
                for (int k = 0; k < 9; ++k) {
                    int dy = k / 3, dx = k % 3;
                    int ib = ((r + dy) * GSL + px + dx) * CI;
                    float d0 = s_u[ib + 0] - c0;
                    float d1 = s_u[ib + 1] - c1;
                    float d2 = s_u[ib + 2] - c2;
                    float w = __expf(-8.0f * (d0 * d0 + d1 * d1 + d2 * d2)) * w1k[k];
                    wv[k] = w;
                    den += w;
                }
                float inv = 1.0f / den;
                #pragma unroll
                for (int k = 0; k < 9; ++k) wreg[ii][k] = wv[k] * inv;
            }
        }
    }
    __syncthreads();   // all guide reads done; s_u may now be overwritten

    // ---- write weight table into the SAME LDS region ----
    #pragma unroll
    for (int ii = 0; ii < 2; ++ii) {
        int idx = ii * TPB + t;
        if (idx < NSETS) {
            float* wd = &s_u[idx * 12];
            *(float4*)(wd + 0) = make_float4(wreg[ii][0], wreg[ii][1], wreg[ii][2], wreg[ii][3]);
            *(float4*)(wd + 4) = make_float4(wreg[ii][4], wreg[ii][5], wreg[ii][6], wreg[ii][7]);
            wd[8] = wreg[ii][8];
        }
    }
    __syncthreads();

    // ---- phase 2: 8-row vertical run, taps from global, weights from LDS ----
    float* ob = out + ((size_t)(b * H + y0)) * rs + (size_t)x0 * CS;

    LOAD3(va0[4], 4, om0, oc0, op0)
    LOAD3(va0[5], 5, om0, oc0, op0)
    float4 vb0[4][3];
    #pragma unroll
    for (int rr = 0; rr < 4; ++rr) { LOAD3(vb0[rr], rr + 6, om0, oc0, op0) }
    COMPUTE8(va0, vb0, px0, oc0)
}

extern "C" void kernel_launch(void* const* d_in, const int* in_sizes, int n_in,
                              void* d_out, int out_size, void* d_ws, size_t ws_size,
                              hipStream_t stream) {
    const float* src = (const float*)d_in[0];
    const float* im  = (const float*)d_in[1];
    float* out = (float*)d_out;
    dim3 grid((W / P) * (H / R) * BATCH, 1, 1);   // 2048 blocks
    jbu_kernel<<<grid, TPB, 0, stream>>>(src, im, out);
}